// Round 5
// baseline (148.991 us; speedup 1.0000x reference)
//
#include <hip/hip_runtime.h>
#include <math.h>

#define B_ 64
#define Q_ 900
#define C_ 256
#define T_ 100
#define N_ 100            // min(Q,T)
#define BIGF 1.0e30f
#define ROWS_PER_LANE 15  // ceil(900/64)

typedef unsigned int u32;
typedef unsigned long long ull;

// ---------------------------------------------------------------------------
// Fused cost kernel: one WAVE per (b,q) row. Identical math/order to rounds
// 1-4 (bit-identical cost matrix; greedy picks depend on it).
// ---------------------------------------------------------------------------
__global__ __launch_bounds__(256) void hm_cost_fused(
    const float* __restrict__ logits,   // [B,Q,C]
    const float* __restrict__ pboxes,   // [B,Q,4] cxcywh
    const int*   __restrict__ tlabels,  // [B,T]
    const float* __restrict__ tboxes,   // [B,T,4] cxcywh
    float* __restrict__ cost)           // [B,Q,T]
{
    int gtid = blockIdx.x * blockDim.x + threadIdx.x;
    int bq   = gtid >> 6;               // wave id == (b,q)
    int lane = threadIdx.x & 63;
    int wid  = threadIdx.x >> 6;        // 0..3
    if (bq >= B_ * Q_) return;
    int b = bq / Q_;

    __shared__ double s_exp[4][C_];     // 8 KB

    const float* row = logits + (size_t)bq * C_;
    float v[4];
    float m = -INFINITY;
#pragma unroll
    for (int i = 0; i < 4; ++i) {
        v[i] = row[lane + 64 * i];
        m = fmaxf(m, v[i]);
    }
#pragma unroll
    for (int off = 32; off >= 1; off >>= 1)
        m = fmaxf(m, __shfl_xor(m, off, 64));

    double e[4];
    double s = 0.0;
#pragma unroll
    for (int i = 0; i < 4; ++i) {
        e[i] = exp((double)v[i] - (double)m);
        s += e[i];
    }
#pragma unroll
    for (int off = 32; off >= 1; off >>= 1)
        s += __shfl_xor(s, off, 64);

#pragma unroll
    for (int i = 0; i < 4; ++i)
        s_exp[wid][lane + 64 * i] = e[i];

    const float* pb = pboxes + (size_t)bq * 4;
    double pcx = pb[0], pcy = pb[1], pw = pb[2], ph = pb[3];

    double px1 = pcx - 0.5 * pw, py1 = pcy - 0.5 * ph;
    double px2 = pcx + 0.5 * pw, py2 = pcy + 0.5 * ph;
    double area1 = fmax(px2 - px1, 0.0) * fmax(py2 - py1, 0.0);

#pragma unroll
    for (int e2 = 0; e2 < 2; ++e2) {
        int t = lane + 64 * e2;
        if (t < T_) {
            int lab = tlabels[b * T_ + t];
            double prob = s_exp[wid][lab] / s;

            const float* tb = tboxes + ((size_t)b * T_ + t) * 4;
            double tcx = tb[0], tcy = tb[1], tw = tb[2], th = tb[3];

            double l1 = fabs(pcx - tcx) + fabs(pcy - tcy) + fabs(pw - tw) + fabs(ph - th);

            double tx1 = tcx - 0.5 * tw, ty1 = tcy - 0.5 * th;
            double tx2 = tcx + 0.5 * tw, ty2 = tcy + 0.5 * th;

            double area2 = fmax(tx2 - tx1, 0.0) * fmax(ty2 - ty1, 0.0);

            double iw = fmax(fmin(px2, tx2) - fmax(px1, tx1), 0.0);
            double ih = fmax(fmin(py2, ty2) - fmax(py1, ty1), 0.0);
            double inter = iw * ih;
            double uni = area1 + area2 - inter;
            double iou = inter / fmax(uni, 1e-6);

            double ew = fmax(fmax(px2, tx2) - fmin(px1, tx1), 0.0);
            double eh = fmax(fmax(py2, ty2) - fmin(py1, ty1), 0.0);
            double earea = ew * eh;
            double giou = iou - (earea - uni) / fmax(earea, 1e-6);

            double c = -prob + 5.0 * l1 - 2.0 * giou;
            cost[(size_t)bq * T_ + t] = (float)c;
        }
    }
}

// ---------------------------------------------------------------------------
// Order-preserving f32 <-> u32 map.
// ---------------------------------------------------------------------------
__device__ inline u32 hm_ordf(float v) {
    u32 u = __float_as_uint(v);
    return (u & 0x80000000u) ? ~u : (u | 0x80000000u);
}
__device__ inline float hm_unordf(u32 e) {
    u32 u = (e & 0x80000000u) ? (e & 0x7FFFFFFFu) : ~e;
    return __uint_as_float(u);
}

// ---------------------------------------------------------------------------
// DPP wave-wide min of u32; returns the min as a wave-uniform value.
// Implemented as ~max(~x): identity for max is 0, which is what invalid DPP
// source lanes contribute under either bound_ctrl semantic (old=0 passed too),
// so the reduction is robust. Sequence: row_shr 1/2/4/8 (within 16-lane
// rows), row_bcast15, row_bcast31 -> lane 63 holds the full 64-lane result.
// VALU-pipe only (~8 cyc/stage) vs ~120 cyc/level for ds_bpermute shuffles.
// ---------------------------------------------------------------------------
__device__ inline u32 hm_umax(u32 a, u32 b) { return a > b ? a : b; }

__device__ inline u32 hm_wave_min_u32(u32 x) {
    u32 y = ~x;
    y = hm_umax(y, (u32)__builtin_amdgcn_update_dpp(0, (int)y, 0x111, 0xF, 0xF, false)); // row_shr:1
    y = hm_umax(y, (u32)__builtin_amdgcn_update_dpp(0, (int)y, 0x112, 0xF, 0xF, false)); // row_shr:2
    y = hm_umax(y, (u32)__builtin_amdgcn_update_dpp(0, (int)y, 0x114, 0xF, 0xF, false)); // row_shr:4
    y = hm_umax(y, (u32)__builtin_amdgcn_update_dpp(0, (int)y, 0x118, 0xF, 0xF, false)); // row_shr:8
    y = hm_umax(y, (u32)__builtin_amdgcn_update_dpp(0, (int)y, 0x142, 0xF, 0xF, false)); // row_bcast15
    y = hm_umax(y, (u32)__builtin_amdgcn_update_dpp(0, (int)y, 0x143, 0xF, 0xF, false)); // row_bcast31
    return ~((u32)__builtin_amdgcn_readlane((int)y, 63));
}

// ---------------------------------------------------------------------------
// Greedy assignment: ONE WAVE per batch. Phase 0: coalesced row-major sweep
// computes per-column minima directly into the owning lane's registers
// (lane l owns columns l and 64+l). Then 100 rounds; each round:
//   phase 1: wave-min over ordered value (DPP, uniform result)
//   phase 2: wave-min over flat id (q<<7|t) among value-ties  -> exact
//            jnp.argmin flat-order semantics (q*128+t is lex-monotone).
// Removing a row invalidates only columns whose cached argmin row == q
// (expected ~0.1/pick) -> wave-parallel column rescan with the same 2-phase
// DPP reduction.
// ---------------------------------------------------------------------------
__global__ __launch_bounds__(64) void hm_greedy_dpp(
    const float* __restrict__ cost,     // [B,Q,T]
    float* __restrict__ out_src,        // [B,N]
    float* __restrict__ out_tgt)        // [B,N]
{
    int b = blockIdx.x;
    int l = threadIdx.x;                // 0..63
    const float* Cb = cost + (size_t)b * Q_ * T_;

    int  t0 = l, t1 = 64 + l;
    bool act0 = true;
    bool act1 = (t1 < T_);
    int  t1c  = act1 ? t1 : 0;          // clamped load index (avoid OOB)

    // ---- phase 0: column minima via coalesced row sweep ----
    float cmin0 = BIGF, cmin1 = BIGF;
    int   carg0 = 0,    carg1 = 0;
#pragma unroll 4
    for (int r = 0; r < Q_; ++r) {
        float v0 = Cb[(size_t)r * T_ + t0];
        float v1 = Cb[(size_t)r * T_ + t1c];
        if (v0 < cmin0) { cmin0 = v0; carg0 = r; }   // strict <: smallest r on ties
        if (v1 < cmin1) { cmin1 = v1; carg1 = r; }
    }

    unsigned removed = 0u;  // bit i => row (l + 64*i) removed

    for (int k = 0; k < N_; ++k) {
        // ---- pick: 2-phase DPP argmin over active columns
        u32 o0 = act0 ? hm_ordf(cmin0) : 0xFFFFFFFFu;
        u32 o1 = act1 ? hm_ordf(cmin1) : 0xFFFFFFFFu;
        u32 minv = hm_wave_min_u32(o0 < o1 ? o0 : o1);

        u32 id = 0xFFFFFFFFu;
        if (o0 == minv) id = ((u32)carg0 << 7) | (u32)t0;
        if (o1 == minv) {
            u32 c2 = ((u32)carg1 << 7) | (u32)t1;
            id = (c2 < id) ? c2 : id;
        }
        u32 fl = hm_wave_min_u32(id);
        int q = (int)(fl >> 7);
        int t = (int)(fl & 127u);

        if (l == 0) {
            out_src[b * N_ + k] = (float)q;
            out_tgt[b * N_ + k] = (float)t;
        }

        // ---- remove column t and row q
        if (t0 == t) act0 = false;
        if (t1 == t) act1 = false;
        if ((q & 63) == l) removed |= 1u << (q >> 6);

        // ---- rescan columns whose cached argmin row just died
        ull bal0 = __ballot(act0 && carg0 == q);
        ull bal1 = __ballot(act1 && carg1 == q);

        while (bal0 | bal1) {
            int tc, owner_entry, owner_lane;
            if (bal0) {
                int p = __ffsll(bal0) - 1;
                bal0 &= bal0 - 1;
                tc = p; owner_entry = 0; owner_lane = p;
            } else {
                int p = __ffsll(bal1) - 1;
                bal1 &= bal1 - 1;
                tc = 64 + p; owner_entry = 1; owner_lane = p;
            }
            // wave-parallel rescan of column tc
            float mv = BIGF;
            int   ma = 0;
#pragma unroll
            for (int i = 0; i < ROWS_PER_LANE; ++i) {
                int r = l + 64 * i;
                bool ok = (r < Q_) && !((removed >> i) & 1u);
                float v = ok ? Cb[(size_t)r * T_ + tc] : BIGF;
                if (v < mv) { mv = v; ma = r; }      // ascending r: smallest on ties
            }
            u32 om = hm_ordf(mv);
            u32 mo = hm_wave_min_u32(om);
            u32 rid = (om == mo) ? (u32)ma : 0xFFFFFFFFu;
            u32 rr = hm_wave_min_u32(rid);
            float nv = hm_unordf(mo);
            int   nr = (int)rr;
            if (owner_entry == 0) {
                if (l == owner_lane) { cmin0 = nv; carg0 = nr; }
            } else {
                if (l == owner_lane) { cmin1 = nv; carg1 = nr; }
            }
        }
    }
}

// ---------------------------------------------------------------------------
extern "C" void kernel_launch(void* const* d_in, const int* in_sizes, int n_in,
                              void* d_out, int out_size, void* d_ws, size_t ws_size,
                              hipStream_t stream)
{
    const float* pred_logits = (const float*)d_in[0];  // [B,Q,C]
    const float* pred_boxes  = (const float*)d_in[1];  // [B,Q,4]
    const int*   tgt_labels  = (const int*)d_in[2];    // [B,T]
    const float* tgt_boxes   = (const float*)d_in[3];  // [B,T,4]

    float* out_cost = (float*)d_out;                       // [B,Q,T]
    float* out_src  = out_cost + (size_t)B_ * Q_ * T_;     // [B,N]
    float* out_tgt  = out_src  + (size_t)B_ * N_;          // [B,N]

    // 1: fused softmax + cost — one wave per (b,q)
    {
        int waves  = B_ * Q_;                  // 57600
        int blocks = waves / 4;                // 4 waves/block
        hm_cost_fused<<<blocks, 256, 0, stream>>>(pred_logits, pred_boxes,
                                                  tgt_labels, tgt_boxes, out_cost);
    }
    // 2: greedy assignment — one wave per batch; fused colmin init + DPP rounds
    hm_greedy_dpp<<<B_, 64, 0, stream>>>(out_cost, out_src, out_tgt);
}

// Round 7
// 140.471 us; speedup vs baseline: 1.0607x; 1.0607x over previous
//
#include <hip/hip_runtime.h>
#include <math.h>

#define B_ 64
#define Q_ 900
#define C_ 256
#define T_ 100
#define N_ 100            // min(Q,T)
#define BIGF 1.0e30f
#define ROWS_PER_LANE 15  // ceil(900/64)
#define CHUNKS 15         // ceil(900/64) row-chunks for colmin partials

typedef unsigned int u32;
typedef unsigned long long ull;

// ---------------------------------------------------------------------------
// Fused cost kernel: one WAVE per (b,q) row. Identical math/order to rounds
// 1-5 (bit-identical cost matrix; greedy picks depend on it).
// ---------------------------------------------------------------------------
__global__ __launch_bounds__(256) void hm_cost_fused(
    const float* __restrict__ logits,   // [B,Q,C]
    const float* __restrict__ pboxes,   // [B,Q,4] cxcywh
    const int*   __restrict__ tlabels,  // [B,T]
    const float* __restrict__ tboxes,   // [B,T,4] cxcywh
    float* __restrict__ cost)           // [B,Q,T]
{
    int gtid = blockIdx.x * blockDim.x + threadIdx.x;
    int bq   = gtid >> 6;               // wave id == (b,q)
    int lane = threadIdx.x & 63;
    int wid  = threadIdx.x >> 6;        // 0..3
    if (bq >= B_ * Q_) return;
    int b = bq / Q_;

    __shared__ double s_exp[4][C_];     // 8 KB

    const float* row = logits + (size_t)bq * C_;
    float v[4];
    float m = -INFINITY;
#pragma unroll
    for (int i = 0; i < 4; ++i) {
        v[i] = row[lane + 64 * i];
        m = fmaxf(m, v[i]);
    }
#pragma unroll
    for (int off = 32; off >= 1; off >>= 1)
        m = fmaxf(m, __shfl_xor(m, off, 64));

    double e[4];
    double s = 0.0;
#pragma unroll
    for (int i = 0; i < 4; ++i) {
        e[i] = exp((double)v[i] - (double)m);
        s += e[i];
    }
#pragma unroll
    for (int off = 32; off >= 1; off >>= 1)
        s += __shfl_xor(s, off, 64);

#pragma unroll
    for (int i = 0; i < 4; ++i)
        s_exp[wid][lane + 64 * i] = e[i];

    const float* pb = pboxes + (size_t)bq * 4;
    double pcx = pb[0], pcy = pb[1], pw = pb[2], ph = pb[3];

    double px1 = pcx - 0.5 * pw, py1 = pcy - 0.5 * ph;
    double px2 = pcx + 0.5 * pw, py2 = pcy + 0.5 * ph;
    double area1 = fmax(px2 - px1, 0.0) * fmax(py2 - py1, 0.0);

#pragma unroll
    for (int e2 = 0; e2 < 2; ++e2) {
        int t = lane + 64 * e2;
        if (t < T_) {
            int lab = tlabels[b * T_ + t];
            double prob = s_exp[wid][lab] / s;

            const float* tb = tboxes + ((size_t)b * T_ + t) * 4;
            double tcx = tb[0], tcy = tb[1], tw = tb[2], th = tb[3];

            double l1 = fabs(pcx - tcx) + fabs(pcy - tcy) + fabs(pw - tw) + fabs(ph - th);

            double tx1 = tcx - 0.5 * tw, ty1 = tcy - 0.5 * th;
            double tx2 = tcx + 0.5 * tw, ty2 = tcy + 0.5 * th;

            double area2 = fmax(tx2 - tx1, 0.0) * fmax(ty2 - ty1, 0.0);

            double iw = fmax(fmin(px2, tx2) - fmax(px1, tx1), 0.0);
            double ih = fmax(fmin(py2, ty2) - fmax(py1, ty1), 0.0);
            double inter = iw * ih;
            double uni = area1 + area2 - inter;
            double iou = inter / fmax(uni, 1e-6);

            double ew = fmax(fmax(px2, tx2) - fmin(px1, tx1), 0.0);
            double eh = fmax(fmax(py2, ty2) - fmin(py1, ty1), 0.0);
            double earea = ew * eh;
            double giou = iou - (earea - uni) / fmax(earea, 1e-6);

            double c = -prob + 5.0 * l1 - 2.0 * giou;
            cost[(size_t)bq * T_ + t] = (float)c;
        }
    }
}

// ---------------------------------------------------------------------------
// Order-preserving f32 -> u32 map. Column key = (ordf(v)<<10) | row (42 bits):
// u64 min == lexicographic (value, row). Round key = colkey<<7 | t ==
// lexicographic (value, q, t) == jnp.argmin flat order.
// ---------------------------------------------------------------------------
__device__ inline u32 hm_ordf(float v) {
    u32 u = __float_as_uint(v);
    return (u & 0x80000000u) ? ~u : (u | 0x80000000u);
}

// ---------------------------------------------------------------------------
// Colmin partials: one block per (batch, 64-row chunk). Stages the row-major
// slab coalesced into LDS, then threads 0..99 reduce their column from LDS.
// Output: INVERTED key ~((ordf<<10)|row) per (b,chunk,t); 0 never wins max.
// ---------------------------------------------------------------------------
__global__ __launch_bounds__(256) void hm_colmin_part(
    const float* __restrict__ cost,     // [B,Q,T]
    ull* __restrict__ part)             // [B,CHUNKS,T] inverted keys
{
    int bc = blockIdx.x;
    int b  = bc / CHUNKS;
    int c  = bc % CHUNKS;
    int tid = threadIdx.x;
    int rows = Q_ - 64 * c; if (rows > 64) rows = 64;
    int n = rows * T_;

    __shared__ float tile[64 * T_];     // 25.6 KB
    const float* src = cost + (size_t)b * Q_ * T_ + (size_t)c * 64 * T_;
    for (int i = tid; i < n; i += 256) tile[i] = src[i];
    __syncthreads();

    if (tid < T_) {
        ull best = 0ull;
        for (int r0 = 0; r0 < rows; ++r0) {
            float v = tile[r0 * T_ + tid];
            ull kk = ~(((ull)hm_ordf(v) << 10) | (u32)(c * 64 + r0));
            best = (kk > best) ? kk : best;   // inverted: max == min key
        }
        part[((size_t)b * CHUNKS + c) * T_ + tid] = best;
    }
}

// ---------------------------------------------------------------------------
// u64 DPP helpers. Template parameter keeps dpp_ctrl a compile-time literal
// (builtin requires it). update_dpp(old=0,...): invalid source lanes yield 0,
// inert under max-of-inverted-keys. Stage sequence row_shr 1/2/4/8,
// row_bcast15, row_bcast31 -> lane 63 holds the 64-lane reduction.
// ---------------------------------------------------------------------------
template <int CTRL>
__device__ inline ull hm_dpp64(ull x) {
    u32 lo = (u32)x, hi = (u32)(x >> 32);
    lo = (u32)__builtin_amdgcn_update_dpp(0, (int)lo, CTRL, 0xF, 0xF, false);
    hi = (u32)__builtin_amdgcn_update_dpp(0, (int)hi, CTRL, 0xF, 0xF, false);
    return ((ull)hi << 32) | lo;
}

// single max-reduction over inverted keys; returns wave-uniform result
__device__ inline ull hm_wave_max_u64(ull x) {
    ull p;
    p = hm_dpp64<0x111>(x); x = (p > x) ? p : x;   // row_shr:1
    p = hm_dpp64<0x112>(x); x = (p > x) ? p : x;   // row_shr:2
    p = hm_dpp64<0x114>(x); x = (p > x) ? p : x;   // row_shr:4
    p = hm_dpp64<0x118>(x); x = (p > x) ? p : x;   // row_shr:8
    p = hm_dpp64<0x142>(x); x = (p > x) ? p : x;   // row_bcast:15
    p = hm_dpp64<0x143>(x); x = (p > x) ? p : x;   // row_bcast:31
    u32 lo = (u32)__builtin_amdgcn_readlane((int)(u32)x, 63);
    u32 hi = (u32)__builtin_amdgcn_readlane((int)(u32)(x >> 32), 63);
    return ((ull)hi << 32) | lo;
}

// one top-2 merge stage: (ka,kb) := top-2 distinct keys of
// {ka,kb} ∪ {dpp(ka),dpp(kb)}  (max semantics on inverted keys)
#define HM_TOP2_STAGE(CTRL)                                                    \
    {                                                                          \
        ull pa = hm_dpp64<CTRL>(ka);                                           \
        ull pb = hm_dpp64<CTRL>(kb);                                           \
        ull na = (ka > pa) ? ka : pa;                                          \
        ull m1 = (ka > pa) ? pa : ka;                                          \
        ull c1 = (m1 == na) ? 0ull : m1;                                       \
        ull c2 = (kb == na) ? 0ull : kb;                                       \
        ull c3 = (pb == na) ? 0ull : pb;                                       \
        ull tm = (c2 > c3) ? c2 : c3;                                          \
        kb = (tm > c1) ? tm : c1;                                              \
        ka = na;                                                               \
    }

// ---------------------------------------------------------------------------
// Greedy: ONE WAVE per batch. Phase 0: merge CHUNKS partials per column into
// registers. Rounds: top-2 sorted-pair DPP scan on inverted round keys
// (dedup by key uniqueness keeps the scan set-idempotent); take 2 picks per
// round when q2 != q1 (same validity condition as the R4 kernel, which
// passed: pick2's column argmin != q1 so its cached min stays exact, and all
// other stored keys lower-bound their post-removal keys).
// ---------------------------------------------------------------------------
__global__ __launch_bounds__(64) void hm_greedy_top2(
    const float* __restrict__ cost,     // [B,Q,T]
    const ull* __restrict__ part,       // [B,CHUNKS,T] inverted keys
    float* __restrict__ out_src,        // [B,N]
    float* __restrict__ out_tgt)        // [B,N]
{
    int b = blockIdx.x;
    int l = threadIdx.x;                // 0..63
    const float* Cb = cost + (size_t)b * Q_ * T_;

    int  t0 = l, t1 = 64 + l;
    bool act0 = true;
    bool act1 = (t1 < T_);

    // ---- phase 0: merge partials (inverted keys; max == min) ----
    ull ck0inv = 0ull, ck1inv = 0ull;
#pragma unroll
    for (int c = 0; c < CHUNKS; ++c) {
        ull p0 = part[((size_t)b * CHUNKS + c) * T_ + t0];
        ck0inv = (p0 > ck0inv) ? p0 : ck0inv;
        if (act1) {
            ull p1 = part[((size_t)b * CHUNKS + c) * T_ + t1];
            ck1inv = (p1 > ck1inv) ? p1 : ck1inv;
        }
    }
    ull colkey0 = ~ck0inv;              // (ordf<<10)|row
    ull colkey1 = act1 ? ~ck1inv : 0ull;

    unsigned removed = 0u;              // bit i => row (l + 64*i) removed

    int k = 0;
    while (k < N_) {
        // ---- per-lane sorted (desc) pair of INVERTED round keys
        ull K0 = act0 ? ~((colkey0 << 7) | (u32)t0) : 0ull;
        ull K1 = act1 ? ~((colkey1 << 7) | (u32)t1) : 0ull;
        ull ka = (K0 > K1) ? K0 : K1;
        ull kbt = (K0 > K1) ? K1 : K0;
        ull kb = (kbt == ka) ? 0ull : kbt;   // dedup (both-0 case)

        // ---- top-2 DPP scan (max over inverted keys)
        HM_TOP2_STAGE(0x111);   // row_shr:1
        HM_TOP2_STAGE(0x112);   // row_shr:2
        HM_TOP2_STAGE(0x114);   // row_shr:4
        HM_TOP2_STAGE(0x118);   // row_shr:8
        HM_TOP2_STAGE(0x142);   // row_bcast:15
        HM_TOP2_STAGE(0x143);   // row_bcast:31

        u32 aLo = (u32)__builtin_amdgcn_readlane((int)(u32)ka, 63);
        u32 aHi = (u32)__builtin_amdgcn_readlane((int)(u32)(ka >> 32), 63);
        u32 bLo = (u32)__builtin_amdgcn_readlane((int)(u32)kb, 63);
        u32 bHi = (u32)__builtin_amdgcn_readlane((int)(u32)(kb >> 32), 63);
        ull inv1 = ((ull)aHi << 32) | aLo;
        ull inv2 = ((ull)bHi << 32) | bLo;

        ull key1 = ~inv1;
        int q1  = (int)((key1 >> 7) & 1023u);
        int tt1 = (int)(key1 & 127u);

        ull key2 = ~inv2;
        int q2  = (int)((key2 >> 7) & 1023u);
        int tt2 = (int)(key2 & 127u);
        bool dbl = (k + 1 < N_) && (inv2 != 0ull) && (q2 != q1);

        if (l == 0) {
            out_src[b * N_ + k] = (float)q1;
            out_tgt[b * N_ + k] = (float)tt1;
            if (dbl) {
                out_src[b * N_ + k + 1] = (float)q2;
                out_tgt[b * N_ + k + 1] = (float)tt2;
            }
        }

        // ---- deactivate picked columns, mark removed rows
        if (t0 == tt1 || (dbl && t0 == tt2)) act0 = false;
        if (t1 == tt1 || (dbl && t1 == tt2)) act1 = false;
        if ((q1 & 63) == l) removed |= 1u << (q1 >> 6);
        if (dbl && (q2 & 63) == l) removed |= 1u << (q2 >> 6);

        // ---- rescan columns whose cached argmin row just died
        int r0 = (int)(colkey0 & 1023u);
        int r1 = (int)(colkey1 & 1023u);
        bool h0 = act0 && (r0 == q1 || (dbl && r0 == q2));
        bool h1 = act1 && (r1 == q1 || (dbl && r1 == q2));
        ull bal0 = __ballot(h0);
        ull bal1 = __ballot(h1);

        while (bal0 | bal1) {
            int tc, owner_entry, owner_lane;
            if (bal0) {
                int p = __ffsll(bal0) - 1;
                bal0 &= bal0 - 1;
                tc = p; owner_entry = 0; owner_lane = p;
            } else {
                int p = __ffsll(bal1) - 1;
                bal1 &= bal1 - 1;
                tc = 64 + p; owner_entry = 1; owner_lane = p;
            }
            // wave-parallel rescan of column tc (single inverted-max chain)
            ull best = 0ull;
#pragma unroll
            for (int i = 0; i < ROWS_PER_LANE; ++i) {
                int r = l + 64 * i;
                bool ok = (r < Q_) && !((removed >> i) & 1u);
                float v = ok ? Cb[(size_t)r * T_ + tc] : BIGF;
                ull kk = ok ? ~(((ull)hm_ordf(v) << 10) | (u32)r) : 0ull;
                best = (kk > best) ? kk : best;
            }
            ull res = hm_wave_max_u64(best);
            ull nk = ~res;                        // new colkey
            if (owner_entry == 0) {
                if (l == owner_lane) colkey0 = nk;
            } else {
                if (l == owner_lane) colkey1 = nk;
            }
        }

        k += dbl ? 2 : 1;
    }
}

// ---------------------------------------------------------------------------
extern "C" void kernel_launch(void* const* d_in, const int* in_sizes, int n_in,
                              void* d_out, int out_size, void* d_ws, size_t ws_size,
                              hipStream_t stream)
{
    const float* pred_logits = (const float*)d_in[0];  // [B,Q,C]
    const float* pred_boxes  = (const float*)d_in[1];  // [B,Q,4]
    const int*   tgt_labels  = (const int*)d_in[2];    // [B,T]
    const float* tgt_boxes   = (const float*)d_in[3];  // [B,T,4]

    float* out_cost = (float*)d_out;                       // [B,Q,T]
    float* out_src  = out_cost + (size_t)B_ * Q_ * T_;     // [B,N]
    float* out_tgt  = out_src  + (size_t)B_ * N_;          // [B,N]

    ull* part = (ull*)d_ws;                                // [B,CHUNKS,T] 768 KB

    // 1: fused softmax + cost — one wave per (b,q)
    {
        int waves  = B_ * Q_;                  // 57600
        int blocks = waves / 4;                // 4 waves/block
        hm_cost_fused<<<blocks, 256, 0, stream>>>(pred_logits, pred_boxes,
                                                  tgt_labels, tgt_boxes, out_cost);
    }
    // 2: colmin partials — one block per (batch, row-chunk), LDS-staged
    hm_colmin_part<<<B_ * CHUNKS, 256, 0, stream>>>(out_cost, part);

    // 3: greedy — one wave per batch, top-2 u64 DPP rounds
    hm_greedy_top2<<<B_, 64, 0, stream>>>(out_cost, part, out_src, out_tgt);
}

// Round 8
// 136.322 us; speedup vs baseline: 1.0929x; 1.0304x over previous
//
#include <hip/hip_runtime.h>
#include <math.h>

#define B_ 64
#define Q_ 900
#define C_ 256
#define T_ 100
#define N_ 100            // min(Q,T)
#define BIGF 1.0e30f
#define ROWS_PER_LANE 15  // ceil(900/64)
#define CHUNKS 15         // ceil(900/64) row-chunks
#define MPICK 4           // picks attempted per reduction round

typedef unsigned int u32;
typedef unsigned long long ull;

// ---------------------------------------------------------------------------
// Order-preserving f32 -> u32 map. Column key = (ordf(v)<<10) | row:
// u64 min == lexicographic (value, row). Round key = (colkey<<7) | t ==
// lexicographic (value, q, t) == jnp.argmin flat order. All reductions use
// INVERTED keys with max semantics so that 0 is an inert identity.
// ---------------------------------------------------------------------------
__device__ inline u32 hm_ordf(float v) {
    u32 u = __float_as_uint(v);
    return (u & 0x80000000u) ? ~u : (u | 0x80000000u);
}

// ---------------------------------------------------------------------------
// Fused cost + column-min kernel: one block per (batch, 64-row chunk).
// Wave w processes rows r0 + w + 4*j (j = 0,1,...) with the EXACT per-row
// code of rounds 1-7 (same lane mapping, same shuffle reduction order, same
// f64 expression order) -> bit-identical cost matrix. Each lane additionally
// maintains the running column-min (inverted key) for its 2 columns across
// its wave's rows; a 4-wave LDS merge emits the per-chunk partials.
// ---------------------------------------------------------------------------
__global__ __launch_bounds__(256) void hm_cost_colmin(
    const float* __restrict__ logits,   // [B,Q,C]
    const float* __restrict__ pboxes,   // [B,Q,4] cxcywh
    const int*   __restrict__ tlabels,  // [B,T]
    const float* __restrict__ tboxes,   // [B,T,4] cxcywh
    float* __restrict__ cost,           // [B,Q,T]
    ull* __restrict__ part)             // [B,CHUNKS,T] inverted colmin keys
{
    int bc   = blockIdx.x;
    int b    = bc / CHUNKS;
    int c    = bc % CHUNKS;
    int lane = threadIdx.x & 63;
    int wid  = threadIdx.x >> 6;        // 0..3
    int r0   = c * 64;
    int R    = Q_ - r0; if (R > 64) R = 64;

    __shared__ double s_exp[4][C_];     // 8 KB (per-wave slice)
    __shared__ ull    s_part[4][128];   // 4 KB

    // target-side constants for this lane's two columns (loop-invariant)
    int ta = lane, tb = 64 + lane;
    bool hb = (tb < T_);
    int laba = tlabels[b * T_ + ta];
    int labb = hb ? tlabels[b * T_ + tb] : 0;
    const float* tba = tboxes + ((size_t)b * T_ + ta) * 4;
    const float* tbb = tboxes + ((size_t)b * T_ + (hb ? tb : 0)) * 4;
    double tcxa = tba[0], tcya = tba[1], twa = tba[2], tha = tba[3];
    double tcxb = tbb[0], tcyb = tbb[1], twb = tbb[2], thb_ = tbb[3];
    double txa1 = tcxa - 0.5 * twa, tya1 = tcya - 0.5 * tha;
    double txa2 = tcxa + 0.5 * twa, tya2 = tcya + 0.5 * tha;
    double txb1 = tcxb - 0.5 * twb, tyb1 = tcyb - 0.5 * thb_;
    double txb2 = tcxb + 0.5 * twb, tyb2 = tcyb + 0.5 * thb_;
    double area2a = fmax(txa2 - txa1, 0.0) * fmax(tya2 - tya1, 0.0);
    double area2b = fmax(txb2 - txb1, 0.0) * fmax(tyb2 - tyb1, 0.0);

    ull cka = 0ull, ckb = 0ull;         // running inverted colmin keys

    for (int r = r0 + wid; r < r0 + R; r += 4) {
        int bq = b * Q_ + r;

        // ---- softmax stats (identical to rounds 1-7) ----
        const float* row = logits + (size_t)bq * C_;
        float v[4];
        float m = -INFINITY;
#pragma unroll
        for (int i = 0; i < 4; ++i) {
            v[i] = row[lane + 64 * i];
            m = fmaxf(m, v[i]);
        }
#pragma unroll
        for (int off = 32; off >= 1; off >>= 1)
            m = fmaxf(m, __shfl_xor(m, off, 64));

        double e[4];
        double s = 0.0;
#pragma unroll
        for (int i = 0; i < 4; ++i) {
            e[i] = exp((double)v[i] - (double)m);
            s += e[i];
        }
#pragma unroll
        for (int off = 32; off >= 1; off >>= 1)
            s += __shfl_xor(s, off, 64);

#pragma unroll
        for (int i = 0; i < 4; ++i)
            s_exp[wid][lane + 64 * i] = e[i];

        // ---- pred-box (identical) ----
        const float* pb = pboxes + (size_t)bq * 4;
        double pcx = pb[0], pcy = pb[1], pw = pb[2], ph = pb[3];
        double px1 = pcx - 0.5 * pw, py1 = pcy - 0.5 * ph;
        double px2 = pcx + 0.5 * pw, py2 = pcy + 0.5 * ph;
        double area1 = fmax(px2 - px1, 0.0) * fmax(py2 - py1, 0.0);

        // ---- entry (r, ta) ----
        {
            double prob = s_exp[wid][laba] / s;
            double l1 = fabs(pcx - tcxa) + fabs(pcy - tcya) + fabs(pw - twa) + fabs(ph - tha);
            double iw = fmax(fmin(px2, txa2) - fmax(px1, txa1), 0.0);
            double ih = fmax(fmin(py2, tya2) - fmax(py1, tya1), 0.0);
            double inter = iw * ih;
            double uni = area1 + area2a - inter;
            double iou = inter / fmax(uni, 1e-6);
            double ew = fmax(fmax(px2, txa2) - fmin(px1, txa1), 0.0);
            double eh = fmax(fmax(py2, tya2) - fmin(py1, tya1), 0.0);
            double earea = ew * eh;
            double giou = iou - (earea - uni) / fmax(earea, 1e-6);
            double cst = -prob + 5.0 * l1 - 2.0 * giou;
            float cf = (float)cst;
            cost[(size_t)bq * T_ + ta] = cf;
            ull kk = ~(((ull)hm_ordf(cf) << 10) | (u32)r);
            cka = (kk > cka) ? kk : cka;
        }
        // ---- entry (r, tb) ----
        if (hb) {
            double prob = s_exp[wid][labb] / s;
            double l1 = fabs(pcx - tcxb) + fabs(pcy - tcyb) + fabs(pw - twb) + fabs(ph - thb_);
            double iw = fmax(fmin(px2, txb2) - fmax(px1, txb1), 0.0);
            double ih = fmax(fmin(py2, tyb2) - fmax(py1, tyb1), 0.0);
            double inter = iw * ih;
            double uni = area1 + area2b - inter;
            double iou = inter / fmax(uni, 1e-6);
            double ew = fmax(fmax(px2, txb2) - fmin(px1, txb1), 0.0);
            double eh = fmax(fmax(py2, tyb2) - fmin(py1, tyb1), 0.0);
            double earea = ew * eh;
            double giou = iou - (earea - uni) / fmax(earea, 1e-6);
            double cst = -prob + 5.0 * l1 - 2.0 * giou;
            float cf = (float)cst;
            cost[(size_t)bq * T_ + tb] = cf;
            ull kk = ~(((ull)hm_ordf(cf) << 10) | (u32)r);
            ckb = (kk > ckb) ? kk : ckb;
        }
    }

    // ---- 4-wave merge of column partials ----
    s_part[wid][lane]      = cka;
    s_part[wid][64 + lane] = ckb;
    __syncthreads();
    int tid = threadIdx.x;
    if (tid < T_) {
        ull b0 = s_part[0][tid];
        ull b1 = s_part[1][tid];
        ull b2 = s_part[2][tid];
        ull b3 = s_part[3][tid];
        ull m01 = (b0 > b1) ? b0 : b1;
        ull m23 = (b2 > b3) ? b2 : b3;
        part[((size_t)b * CHUNKS + c) * T_ + tid] = (m01 > m23) ? m01 : m23;
    }
}

// ---------------------------------------------------------------------------
// u64 DPP helpers (ctrl must be a literal -> template parameter).
// update_dpp(old=0): invalid source lanes contribute 0 (inert under max).
// ---------------------------------------------------------------------------
template <int CTRL>
__device__ inline ull hm_dpp64(ull x) {
    u32 lo = (u32)x, hi = (u32)(x >> 32);
    lo = (u32)__builtin_amdgcn_update_dpp(0, (int)lo, CTRL, 0xF, 0xF, false);
    hi = (u32)__builtin_amdgcn_update_dpp(0, (int)hi, CTRL, 0xF, 0xF, false);
    return ((ull)hi << 32) | lo;
}

// cheap wave-wide max (5 VALU/stage), result wave-uniform
__device__ inline ull hm_wave_max_u64(ull x) {
    ull p;
    p = hm_dpp64<0x111>(x); x = (p > x) ? p : x;   // row_shr:1
    p = hm_dpp64<0x112>(x); x = (p > x) ? p : x;   // row_shr:2
    p = hm_dpp64<0x114>(x); x = (p > x) ? p : x;   // row_shr:4
    p = hm_dpp64<0x118>(x); x = (p > x) ? p : x;   // row_shr:8
    p = hm_dpp64<0x142>(x); x = (p > x) ? p : x;   // row_bcast:15
    p = hm_dpp64<0x143>(x); x = (p > x) ? p : x;   // row_bcast:31
    u32 lo = (u32)__builtin_amdgcn_readlane((int)(u32)x, 63);
    u32 hi = (u32)__builtin_amdgcn_readlane((int)(u32)(x >> 32), 63);
    return ((ull)hi << 32) | lo;
}

// ---------------------------------------------------------------------------
// Greedy: ONE WAVE per batch. Sequential-kill top-4 per round: reduce ->
// winner -> owner zeroes its candidate -> reduce again. Pick i is valid iff
// its cached argmin row ∉ earlier picks of the round (stored keys lower-bound
// true keys; an exact stored key that wins the max IS the global next pick —
// same argument as the R4 top-2 kernel, applied inductively). On collision:
// break; the stale column is caught by the rescan ballot and fixed.
// ---------------------------------------------------------------------------
__global__ __launch_bounds__(64) void hm_greedy_seq4(
    const float* __restrict__ cost,     // [B,Q,T]
    const ull* __restrict__ part,       // [B,CHUNKS,T] inverted keys
    float* __restrict__ out_src,        // [B,N]
    float* __restrict__ out_tgt)        // [B,N]
{
    int b = blockIdx.x;
    int l = threadIdx.x;                // 0..63
    const float* Cb = cost + (size_t)b * Q_ * T_;

    int  t0 = l, t1 = 64 + l;
    bool act0 = true;
    bool act1 = (t1 < T_);

    // ---- phase 0: merge chunk partials into per-lane column keys ----
    ull ck0inv = 0ull, ck1inv = 0ull;
#pragma unroll
    for (int c = 0; c < CHUNKS; ++c) {
        ull p0 = part[((size_t)b * CHUNKS + c) * T_ + t0];
        ck0inv = (p0 > ck0inv) ? p0 : ck0inv;
        if (act1) {
            ull p1 = part[((size_t)b * CHUNKS + c) * T_ + t1];
            ck1inv = (p1 > ck1inv) ? p1 : ck1inv;
        }
    }
    ull colkey0 = ~ck0inv;              // (ordf<<10)|row
    ull colkey1 = act1 ? ~ck1inv : 0ull;

    unsigned removed = 0u;              // bit i => row (l + 64*i) removed

    int k = 0;
    while (k < N_) {
        // per-lane inverted round keys for the two owned columns
        ull c0 = act0 ? ~((colkey0 << 7) | (u32)t0) : 0ull;
        ull c1 = act1 ? ~((colkey1 << 7) | (u32)t1) : 0ull;

        int pq0 = -1, pt0 = -1, pq1 = -1, pt1v = -1,
            pq2 = -1, pt2 = -1, pq3 = -1, pt3 = -1;
        int p = 0;

#pragma unroll
        for (int i = 0; i < MPICK; ++i) {
            if (p == i && k + i < N_) {
                ull loc = (c0 > c1) ? c0 : c1;
                ull win = hm_wave_max_u64(loc);
                if (win != 0ull) {
                    ull key = ~win;
                    int q = (int)((key >> 7) & 1023u);
                    int t = (int)(key & 127u);
                    bool coll = (q == pq0) || (q == pq1) || (q == pq2);
                    if (!coll) {
                        if (i == 0)      { pq0 = q; pt0  = t; }
                        else if (i == 1) { pq1 = q; pt1v = t; }
                        else if (i == 2) { pq2 = q; pt2  = t; }
                        else             { pq3 = q; pt3  = t; }
                        p = i + 1;
                        if (c0 == win) c0 = 0ull;   // kill (keys unique)
                        if (c1 == win) c1 = 0ull;
                    }
                }
            }
        }

        // ---- emit picks ----
        if (l == 0) {
            if (p > 0) { out_src[b * N_ + k]     = (float)pq0; out_tgt[b * N_ + k]     = (float)pt0; }
            if (p > 1) { out_src[b * N_ + k + 1] = (float)pq1; out_tgt[b * N_ + k + 1] = (float)pt1v; }
            if (p > 2) { out_src[b * N_ + k + 2] = (float)pq2; out_tgt[b * N_ + k + 2] = (float)pt2; }
            if (p > 3) { out_src[b * N_ + k + 3] = (float)pq3; out_tgt[b * N_ + k + 3] = (float)pt3; }
        }

        // ---- deactivate picked columns, mark removed rows ----
        if (t0 == pt0 || t0 == pt1v || t0 == pt2 || t0 == pt3) act0 = false;
        if (t1 == pt0 || t1 == pt1v || t1 == pt2 || t1 == pt3) act1 = false;
        if (p > 0 && (pq0 & 63) == l) removed |= 1u << (pq0 >> 6);
        if (p > 1 && (pq1 & 63) == l) removed |= 1u << (pq1 >> 6);
        if (p > 2 && (pq2 & 63) == l) removed |= 1u << (pq2 >> 6);
        if (p > 3 && (pq3 & 63) == l) removed |= 1u << (pq3 >> 6);

        // ---- rescan columns whose cached argmin row just died ----
        int r0c = (int)(colkey0 & 1023u);
        int r1c = (int)(colkey1 & 1023u);
        bool h0 = act0 && (r0c == pq0 || r0c == pq1 || r0c == pq2 || r0c == pq3);
        bool h1 = act1 && (r1c == pq0 || r1c == pq1 || r1c == pq2 || r1c == pq3);
        ull bal0 = __ballot(h0);
        ull bal1 = __ballot(h1);

        while (bal0 | bal1) {
            int tc, owner_entry, owner_lane;
            if (bal0) {
                int pp = __ffsll(bal0) - 1;
                bal0 &= bal0 - 1;
                tc = pp; owner_entry = 0; owner_lane = pp;
            } else {
                int pp = __ffsll(bal1) - 1;
                bal1 &= bal1 - 1;
                tc = 64 + pp; owner_entry = 1; owner_lane = pp;
            }
            ull best = 0ull;
#pragma unroll
            for (int i = 0; i < ROWS_PER_LANE; ++i) {
                int r = l + 64 * i;
                bool ok = (r < Q_) && !((removed >> i) & 1u);
                float v = ok ? Cb[(size_t)r * T_ + tc] : BIGF;
                ull kk = ok ? ~(((ull)hm_ordf(v) << 10) | (u32)r) : 0ull;
                best = (kk > best) ? kk : best;
            }
            ull res = hm_wave_max_u64(best);
            ull nk = ~res;
            if (owner_entry == 0) {
                if (l == owner_lane) colkey0 = nk;
            } else {
                if (l == owner_lane) colkey1 = nk;
            }
        }

        k += p;
    }
}

// ---------------------------------------------------------------------------
extern "C" void kernel_launch(void* const* d_in, const int* in_sizes, int n_in,
                              void* d_out, int out_size, void* d_ws, size_t ws_size,
                              hipStream_t stream)
{
    const float* pred_logits = (const float*)d_in[0];  // [B,Q,C]
    const float* pred_boxes  = (const float*)d_in[1];  // [B,Q,4]
    const int*   tgt_labels  = (const int*)d_in[2];    // [B,T]
    const float* tgt_boxes   = (const float*)d_in[3];  // [B,T,4]

    float* out_cost = (float*)d_out;                       // [B,Q,T]
    float* out_src  = out_cost + (size_t)B_ * Q_ * T_;     // [B,N]
    float* out_tgt  = out_src  + (size_t)B_ * N_;          // [B,N]

    ull* part = (ull*)d_ws;                                // [B,CHUNKS,T] 768 KB

    // 1: fused softmax + cost + column-min partials
    hm_cost_colmin<<<B_ * CHUNKS, 256, 0, stream>>>(pred_logits, pred_boxes,
                                                    tgt_labels, tgt_boxes,
                                                    out_cost, part);

    // 2: greedy — one wave per batch, sequential-kill top-4 DPP rounds
    hm_greedy_seq4<<<B_, 64, 0, stream>>>(out_cost, part, out_src, out_tgt);
}